// Round 7
// baseline (206.452 us; speedup 1.0000x reference)
//
#include <hip/hip_runtime.h>
#include <hip/hip_bf16.h>
#include <stdint.h>

// Problem dims
#define B_ROWS 8192
#define D_DIM  1024
#define C_CLS  1000
#define K_PROT 8
#define N_PAD  8192          // 32 * 256 (classes 1000..1023 zero-padded)
#define BKT    64            // K-step per tile
#define NT     16            // D_DIM / BKT

typedef __attribute__((ext_vector_type(8))) short  short8;   // 8 bf16
typedef __attribute__((ext_vector_type(4))) float  f32x4;    // MFMA acc

// --- helpers -------------------------------------------------------------

__device__ __forceinline__ ushort f2bf(float f) {
    union { float f; uint32_t u; } v; v.f = f;
    uint32_t u = v.u;
    return (ushort)((u + 0x7fffu + ((u >> 16) & 1u)) >> 16);
}

typedef __attribute__((address_space(1))) void gv_t;
typedef __attribute__((address_space(3))) void lv_t;

__device__ __forceinline__ void gload_lds16(const void* g, void* l) {
    // async global->LDS, 16B/lane; LDS dest = wave-uniform base + lane*16
    __builtin_amdgcn_global_load_lds((gv_t*)g, (lv_t*)l, 16, 0, 0);
}

__device__ __forceinline__ float waveReduceSum(float s) {
    #pragma unroll
    for (int m = 32; m >= 1; m >>= 1) s += __shfl_xor(s, m);
    return s;
}

// --- kernel 1: normalize weight_v rows -> bf16, PERMUTED + padded ---------
// Physical column P: gpan=P>>6 (64-col panel), ni=(P>>4)&3, cc=P&15
//   class = gpan*8 + (cc&7),  k = ni + 4*(cc>>3)
// -> all 8 k's of a class live in lane pair (lane, lane^8) of the epilogue.

__global__ __launch_bounds__(256) void prep_z(const float* __restrict__ wv,
                                              ushort* __restrict__ zb) {
    const int P = blockIdx.x;
    const int t = threadIdx.x;
    __shared__ float red[4];

    const int gpan = P >> 6;
    const int ni   = (P >> 4) & 3;
    const int cc   = P & 15;
    const int cls  = gpan * 8 + (cc & 7);
    const int k    = ni + ((cc >> 3) << 2);

    if (cls >= C_CLS) {
        ((ushort4*)(zb + (size_t)P * D_DIM))[t] = make_ushort4(0, 0, 0, 0);
        return;
    }
    const int n = cls * K_PROT + k;
    const float4 v = ((const float4*)(wv + (size_t)n * D_DIM))[t];
    float s = v.x*v.x + v.y*v.y + v.z*v.z + v.w*v.w;
    s = waveReduceSum(s);
    if ((t & 63) == 0) red[t >> 6] = s;
    __syncthreads();
    const float n2 = red[0] + red[1] + red[2] + red[3];
    const float rn = 1.0f / fmaxf(sqrtf(n2), 1e-15f);
    ushort4 o;
    o.x = f2bf(v.x * rn); o.y = f2bf(v.y * rn);
    o.z = f2bf(v.z * rn); o.w = f2bf(v.w * rn);
    ((ushort4*)(zb + (size_t)P * D_DIM))[t] = o;
}

// --- kernel 2: x -> bf16 + cx2 = sum(x^2) ---------------------------------

__global__ __launch_bounds__(256) void prep_x(const float* __restrict__ x,
                                              ushort* __restrict__ xb,
                                              float* __restrict__ cx2) {
    const int b = blockIdx.x;
    const int t = threadIdx.x;
    __shared__ float red[4];

    const float4 v = ((const float4*)(x + (size_t)b * D_DIM))[t];
    ushort4 o;
    o.x = f2bf(v.x); o.y = f2bf(v.y); o.z = f2bf(v.z); o.w = f2bf(v.w);
    ((ushort4*)(xb + (size_t)b * D_DIM))[t] = o;

    float s = v.x*v.x + v.y*v.y + v.z*v.z + v.w*v.w;
    s = waveReduceSum(s);
    if ((t & 63) == 0) red[t >> 6] = s;
    __syncthreads();
    if (t == 0) cx2[b] = red[0] + red[1] + red[2] + red[3];
}

// --- kernel 3: 256x256, 8 waves, 8-phase K-half pipeline (m201 port) ------
// Buffer b = c&1 (64KB): [A-kk0 | A-kk1 | B-kk0 | B-kk1], each 256x32 bf16
// = 16KB = 2 gload_lds_dwordx4 per wave-set. Phase p of tile c:
//   P1: ds_read A(mi0-3,kk0)+B(ni0-3,kk0); stage A-kk1(c+1); bar; 16 MFMA; bar
//   P2: ds_read A(mi4-7,kk0);              stage B-kk1(c+1); bar; 16 MFMA; bar
//   P3: ds_read A(mi0-3,kk1)+B(ni0-3,kk1); stage A-kk0(c+2); bar; 16 MFMA; bar
//   P4: ds_read A(mi4-7,kk1);              stage B-kk0(c+2); bar; 16 MFMA;
//       vmcnt(4) [tail: (0)]; bar
// Overwrite safety: kk0 regions of buffer c&1 are re-staged at P3/P4, after
// P2's barrier ended all kk0 reads. Boundary vmcnt(4) leaves only kk0(c+2)
// in flight; everything tile c+1 reads has retired. Swizzle (both sides):
// 16B-slot p_phys = p_log ^ (row&3) within each 64B row.

__global__ __launch_bounds__(512, 2) void gemm_epi(
        const ushort* __restrict__ A,    // [B_ROWS][D_DIM] bf16 (x)
        const ushort* __restrict__ Bz,   // [N_PAD][D_DIM] bf16 (permuted z)
        const float*  __restrict__ cx2g, // [B_ROWS]
        const float*  __restrict__ wgl,  // [C_CLS]
        const float*  __restrict__ gamma_p,
        float*        __restrict__ out)  // [B_ROWS][C_CLS]
{
    __shared__ __attribute__((aligned(128))) char lds[131072];

    const int tid  = threadIdx.x;
    const int lane = tid & 63;
    const int wid  = tid >> 6;        // 0..7
    const int wm   = wid >> 2;        // 0..1 : 128 output rows each
    const int wn   = wid & 3;         // 0..3 : 64 output cols each

    // T1 grid: XCD x = bid&7 owns bn in [4x,4x+4) (B-panel 2MB, L2-resident)
    const int bid = blockIdx.x;       // 0..1023
    const int xcd = bid & 7;
    const int j   = bid >> 3;         // 0..127
    const int bn  = xcd * 4 + (j & 3);
    const int bm  = j >> 2;
    const int m0  = bm * 256;
    const int n0  = bn * 256;

    // staging: thread t -> row t>>2 (and +128 for 2nd gload), phys slot t&3,
    // source col-group = (t&3) ^ (row&3)   [T2 swizzle, source side]
    const int aCol = (((tid & 3) ^ ((tid >> 2) & 3)) * 8);
    const ushort* aP = A  + (size_t)(m0 + (tid >> 2)) * D_DIM + aCol;
    const ushort* bP = Bz + (size_t)(n0 + (tid >> 2)) * D_DIM + aCol;
    const int ldsW = wid * 1024;      // wave-uniform sub-base

    // fragment reads: row&3 == lane&3; swizzled slot = (lane>>4) ^ (lane&3)
    const int swz   = (((lane >> 4) ^ (lane & 3)) * 16);
    const int aRowB = (wm * 128 + (lane & 15)) * 64 + swz;   // + mi*1024
    const int bRowB = (wn * 64  + (lane & 15)) * 64 + swz;   // + ni*1024

#define BUF(c)  (lds + ((c) & 1) * 65536)
#define STAGE_A(c, h) do { char* d_ = BUF(c) + (h) * 16384 + ldsW; \
    const ushort* s_ = aP + (c) * BKT + (h) * 32; \
    gload_lds16(s_, d_); \
    gload_lds16(s_ + (size_t)128 * D_DIM, d_ + 8192); } while (0)
#define STAGE_B(c, h) do { char* d_ = BUF(c) + 32768 + (h) * 16384 + ldsW; \
    const ushort* s_ = bP + (c) * BKT + (h) * 32; \
    gload_lds16(s_, d_); \
    gload_lds16(s_ + (size_t)128 * D_DIM, d_ + 8192); } while (0)
#define LDA(c, h, mi) (*(const short8*)(BUF(c) + (h) * 16384 + aRowB + (mi) * 1024))
#define LDB(c, h, ni) (*(const short8*)(BUF(c) + 32768 + (h) * 16384 + bRowB + (ni) * 1024))
#define BAR() do { asm volatile("" ::: "memory"); \
    __builtin_amdgcn_s_barrier(); asm volatile("" ::: "memory"); } while (0)

    f32x4 acc[8][4];
    #pragma unroll
    for (int i = 0; i < 8; ++i)
        #pragma unroll
        for (int q = 0; q < 4; ++q) acc[i][q] = (f32x4)(0.0f);

    // prologue: kk0(0), kk1(0), kk0(1) staged; retire through kk1(0)
    STAGE_A(0, 0); STAGE_B(0, 0); STAGE_A(0, 1); STAGE_B(0, 1);
    STAGE_A(1, 0); STAGE_B(1, 0);
    asm volatile("s_waitcnt vmcnt(4)" ::: "memory");
    BAR();

    for (int c = 0; c < NT; ++c) {
        short8 a[4], b[4];
        // ---- P1: kk0, mi 0-3 ----
        #pragma unroll
        for (int mi = 0; mi < 4; ++mi) a[mi] = LDA(c, 0, mi);
        #pragma unroll
        for (int ni = 0; ni < 4; ++ni) b[ni] = LDB(c, 0, ni);
        if (c + 1 < NT) STAGE_A(c + 1, 1);
        BAR();
        __builtin_amdgcn_s_setprio(1);
        #pragma unroll
        for (int mi = 0; mi < 4; ++mi)
            #pragma unroll
            for (int ni = 0; ni < 4; ++ni)
                acc[mi][ni] = __builtin_amdgcn_mfma_f32_16x16x32_bf16(
                    a[mi], b[ni], acc[mi][ni], 0, 0, 0);
        __builtin_amdgcn_s_setprio(0);
        BAR();
        // ---- P2: kk0, mi 4-7 (reuse b) ----
        #pragma unroll
        for (int mi = 0; mi < 4; ++mi) a[mi] = LDA(c, 0, mi + 4);
        if (c + 1 < NT) STAGE_B(c + 1, 1);
        BAR();
        __builtin_amdgcn_s_setprio(1);
        #pragma unroll
        for (int mi = 0; mi < 4; ++mi)
            #pragma unroll
            for (int ni = 0; ni < 4; ++ni)
                acc[mi + 4][ni] = __builtin_amdgcn_mfma_f32_16x16x32_bf16(
                    a[mi], b[ni], acc[mi + 4][ni], 0, 0, 0);
        __builtin_amdgcn_s_setprio(0);
        BAR();
        // ---- P3: kk1, mi 0-3 ----
        #pragma unroll
        for (int mi = 0; mi < 4; ++mi) a[mi] = LDA(c, 1, mi);
        #pragma unroll
        for (int ni = 0; ni < 4; ++ni) b[ni] = LDB(c, 1, ni);
        if (c + 2 < NT) STAGE_A(c + 2, 0);
        BAR();
        __builtin_amdgcn_s_setprio(1);
        #pragma unroll
        for (int mi = 0; mi < 4; ++mi)
            #pragma unroll
            for (int ni = 0; ni < 4; ++ni)
                acc[mi][ni] = __builtin_amdgcn_mfma_f32_16x16x32_bf16(
                    a[mi], b[ni], acc[mi][ni], 0, 0, 0);
        __builtin_amdgcn_s_setprio(0);
        BAR();
        // ---- P4: kk1, mi 4-7; boundary wait ----
        #pragma unroll
        for (int mi = 0; mi < 4; ++mi) a[mi] = LDA(c, 1, mi + 4);
        if (c + 2 < NT) STAGE_B(c + 2, 0);
        BAR();
        __builtin_amdgcn_s_setprio(1);
        #pragma unroll
        for (int mi = 0; mi < 4; ++mi)
            #pragma unroll
            for (int ni = 0; ni < 4; ++ni)
                acc[mi + 4][ni] = __builtin_amdgcn_mfma_f32_16x16x32_bf16(
                    a[mi], b[ni], acc[mi + 4][ni], 0, 0, 0);
        __builtin_amdgcn_s_setprio(0);
        if (c < NT - 2)       asm volatile("s_waitcnt vmcnt(4)" ::: "memory");
        else if (c == NT - 2) asm volatile("s_waitcnt vmcnt(0)" ::: "memory");
        BAR();
    }

    // ---- fused epilogue: hyperbolic logits + lane-pair logsumexp ---------
    __syncthreads();
    float* scx = (float*)lds;
    if (tid < 256) scx[tid] = cx2g[m0 + tid];
    __syncthreads();

    const float gam = gamma_p[0];
    const float ex  = expf(2.0f * gam);
    const float ch2 = ex + 1.0f / ex;           // 2*cosh(2*gamma)
    const float sh  = 0.5f * (ex - 1.0f / ex);  // sinh(2*gamma)

    const int  pan = (n0 >> 6) + wn;            // 64-col panel index
    const int  cls = pan * 8 + (lane & 7);
    const bool wrt = ((lane & 8) == 0) && (cls < C_CLS);
    const float w2 = (cls < C_CLS) ? 2.0f * wgl[cls] : 0.0f;

    #pragma unroll
    for (int mi = 0; mi < 8; ++mi) {
        #pragma unroll
        for (int r = 0; r < 4; ++r) {
            const int mloc = wm * 128 + mi * 16 + ((lane >> 4) << 2) + r;
            const float c2   = scx[mloc];
            const float rden = 1.0f / fmaxf(1.0f - c2, 1e-15f);
            const float tc   = ch2 * rden;
            const float tp   = (1.0f + c2) * sh * rden;
            float bk[4];
            #pragma unroll
            for (int ni = 0; ni < 4; ++ni) {
                const float t = fmaf(acc[mi][ni][r], tc, -tp);
                const float u = fmaxf(t + __fsqrt_rn(fmaf(t, t, 1.0f)), 1e-20f);
                bk[ni] = w2 * __logf(u);
            }
            float mx = fmaxf(fmaxf(bk[0], bk[1]), fmaxf(bk[2], bk[3]));
            mx = fmaxf(mx, __shfl_xor(mx, 8));
            float s = __expf(bk[0] - mx) + __expf(bk[1] - mx)
                    + __expf(bk[2] - mx) + __expf(bk[3] - mx);
            s += __shfl_xor(s, 8);
            if (wrt)
                out[(size_t)(m0 + mloc) * C_CLS + cls] = mx + __logf(s);
        }
    }
#undef BUF
#undef STAGE_A
#undef STAGE_B
#undef LDA
#undef LDB
#undef BAR
}

// --- launch ----------------------------------------------------------------

extern "C" void kernel_launch(void* const* d_in, const int* in_sizes, int n_in,
                              void* d_out, int out_size, void* d_ws, size_t ws_size,
                              hipStream_t stream) {
    const float* x     = (const float*)d_in[0];
    const float* wv    = (const float*)d_in[1];
    const float* wg    = (const float*)d_in[2];
    const float* gamma = (const float*)d_in[3];
    float* out = (float*)d_out;

    char* ws = (char*)d_ws;
    ushort* xb  = (ushort*)ws;                                  // 16,777,216 B
    ushort* zb  = (ushort*)(ws + (size_t)B_ROWS * D_DIM * 2);   // 16,777,216 B
    float*  cx2 = (float*)(ws + (size_t)B_ROWS * D_DIM * 2
                              + (size_t)N_PAD * D_DIM * 2);     //     32,768 B

    prep_z<<<N_PAD, 256, 0, stream>>>(wv, zb);
    prep_x<<<B_ROWS, 256, 0, stream>>>(x, xb, cx2);
    gemm_epi<<<1024, 512, 0, stream>>>(xb, zb, cx2, wg, gamma, out);
}

// Round 8
// 205.711 us; speedup vs baseline: 1.0036x; 1.0036x over previous
//
#include <hip/hip_runtime.h>
#include <hip/hip_bf16.h>
#include <stdint.h>

// Problem dims
#define B_ROWS 8192
#define D_DIM  1024
#define C_CLS  1000
#define K_PROT 8
#define N_PAD  8192          // 32 * 256 (classes 1000..1023 zero-padded)
#define BM     256
#define BN     256
#define BKT    64            // K-tile depth (elements)
#define NT     16            // D_DIM / BKT

typedef __attribute__((ext_vector_type(8))) short  short8;   // 8 bf16
typedef __attribute__((ext_vector_type(4))) float  f32x4;    // MFMA acc

// --- helpers -------------------------------------------------------------

__device__ __forceinline__ ushort f2bf(float f) {
    union { float f; uint32_t u; } v; v.f = f;
    uint32_t u = v.u;
    return (ushort)((u + 0x7fffu + ((u >> 16) & 1u)) >> 16);
}

typedef __attribute__((address_space(1))) void gv_t;
typedef __attribute__((address_space(3))) void lv_t;

__device__ __forceinline__ void gload_lds16(const void* g, void* l) {
    // async global->LDS, 16B/lane; LDS dest = wave-uniform base + lane*16
    __builtin_amdgcn_global_load_lds((gv_t*)g, (lv_t*)l, 16, 0, 0);
}

__device__ __forceinline__ float waveReduceSum(float s) {
    #pragma unroll
    for (int m = 32; m >= 1; m >>= 1) s += __shfl_xor(s, m);
    return s;
}

// --- kernel 1: fused prep -------------------------------------------------
// blocks 0..8191:      x row b -> bf16 + cx2
// blocks 8192..16383:  weight_v -> normalized bf16, PERMUTED + padded
// Column permutation: physical col P: gpan=P>>6, ni=(P>>4)&3, cc=P&15
//   class = gpan*8 + (cc&7),  k = ni + 4*(cc>>3)
// -> all 8 k's of a class land in lane pair (lane, lane^8) of the epilogue.

__global__ __launch_bounds__(256) void prep(const float* __restrict__ x,
                                            const float* __restrict__ wv,
                                            ushort* __restrict__ xb,
                                            ushort* __restrict__ zb,
                                            float* __restrict__ cx2) {
    const int t = threadIdx.x;
    __shared__ float red[4];

    if ((int)blockIdx.x < B_ROWS) {
        const int b = blockIdx.x;
        const float4 v = ((const float4*)(x + (size_t)b * D_DIM))[t];
        ushort4 o;
        o.x = f2bf(v.x); o.y = f2bf(v.y); o.z = f2bf(v.z); o.w = f2bf(v.w);
        ((ushort4*)(xb + (size_t)b * D_DIM))[t] = o;
        float s = v.x*v.x + v.y*v.y + v.z*v.z + v.w*v.w;
        s = waveReduceSum(s);
        if ((t & 63) == 0) red[t >> 6] = s;
        __syncthreads();
        if (t == 0) cx2[b] = red[0] + red[1] + red[2] + red[3];
        return;
    }

    const int P    = blockIdx.x - B_ROWS;       // 0..N_PAD-1
    const int gpan = P >> 6;
    const int ni   = (P >> 4) & 3;
    const int cc   = P & 15;
    const int cls  = gpan * 8 + (cc & 7);
    const int k    = ni + ((cc >> 3) << 2);

    if (cls >= C_CLS) {
        ((ushort4*)(zb + (size_t)P * D_DIM))[t] = make_ushort4(0, 0, 0, 0);
        return;
    }
    const int n = cls * K_PROT + k;
    const float4 v = ((const float4*)(wv + (size_t)n * D_DIM))[t];
    float s = v.x*v.x + v.y*v.y + v.z*v.z + v.w*v.w;
    s = waveReduceSum(s);
    if ((t & 63) == 0) red[t >> 6] = s;
    __syncthreads();
    const float n2 = red[0] + red[1] + red[2] + red[3];
    const float rn = 1.0f / fmaxf(sqrtf(n2), 1e-15f);
    ushort4 o;
    o.x = f2bf(v.x * rn); o.y = f2bf(v.y * rn);
    o.z = f2bf(v.z * rn); o.w = f2bf(v.w * rn);
    ((ushort4*)(zb + (size_t)P * D_DIM))[t] = o;
}

// --- kernel 2: 256x256 block, 8 waves (128x64 each), R6 2-barrier loop ----
// Single-buffered 64 KB LDS -> 2 blocks/CU co-resident; cross-block overlap
// fills barrier stalls (the mechanism R3/R6 proved; the 128 KiB 1-block/CU
// variants R4/R5/R7 all failed). Swizzle identical to R6 (measured 0
// conflicts): source col-group = (slot) ^ (row&7), 8 x 16B slots per 128 B
// row, same XOR on the fragment-read byte address.

__global__ __launch_bounds__(512, 2) void gemm_epi(
        const ushort* __restrict__ A,    // [B_ROWS][D_DIM] bf16 (x)
        const ushort* __restrict__ Bz,   // [N_PAD][D_DIM] bf16 (permuted z)
        const float*  __restrict__ cx2g, // [B_ROWS]
        const float*  __restrict__ wgl,  // [C_CLS]
        const float*  __restrict__ gamma_p,
        float*        __restrict__ out)  // [B_ROWS][C_CLS]
{
    __shared__ __attribute__((aligned(16))) ushort sA[BM * BKT]; // 32 KB
    __shared__ __attribute__((aligned(16))) ushort sB[BN * BKT]; // 32 KB

    const int tid  = threadIdx.x;
    const int lane = tid & 63;
    const int wid  = tid >> 6;        // 0..7
    const int wm   = wid >> 2;        // 0..1 : 128 output rows each
    const int wn   = wid & 3;         // 0..3 : 64 output cols each

    // XCD grid: xcd owns bn in [4x,4x+4) (B panels 2MB, L2-resident);
    // bn fastest -> 4 consecutive blocks share one A-panel.
    const int bid = blockIdx.x;       // 0..1023
    const int xcd = bid & 7;
    const int j   = bid >> 3;         // 0..127
    const int bn  = xcd * 4 + (j & 3);
    const int bm  = j >> 2;           // 0..31
    const int m0  = bm * BM;
    const int n0  = bn * BN;

    // staging: thread t covers row t>>3 of each 64-row group, 16B slot t&7;
    // source col-group = (t&7) ^ (row&7)   [T2 swizzle, source side]
    const int stCol = ((tid & 7) ^ ((tid >> 3) & 7)) * 8;
    const ushort* aS = A  + (size_t)(m0 + (tid >> 3)) * D_DIM + stCol;
    const ushort* bS = Bz + (size_t)(n0 + (tid >> 3)) * D_DIM + stCol;
    const int ldsW = wid * 1024;      // wave-uniform LDS sub-base

    // fragment reads (128 B rows; same swizzle, proven 0-conflict in R6)
    const int swz0 = ((      (lane >> 4) * 16) ^ ((lane & 7) << 4));
    const int swz1 = ((64 + ((lane >> 4) * 16)) ^ ((lane & 7) << 4));
    const char* sAb = (const char*)sA + (wm * 128 + (lane & 15)) * 128;
    const char* sBb = (const char*)sB + (wn * 64  + (lane & 15)) * 128;

    f32x4 acc[8][4];
    #pragma unroll
    for (int mi = 0; mi < 8; ++mi)
        #pragma unroll
        for (int ni = 0; ni < 4; ++ni)
            acc[mi][ni] = (f32x4)(0.0f);

    for (int t = 0; t < NT; ++t) {
        const int k0 = t * BKT;
        // stage A and B: 4 x 64-row groups each (8 KB per gload-set)
        #pragma unroll
        for (int i = 0; i < 4; ++i)
            gload_lds16(aS + (size_t)i * 64 * D_DIM + k0,
                        (char*)sA + i * 8192 + ldsW);
        #pragma unroll
        for (int i = 0; i < 4; ++i)
            gload_lds16(bS + (size_t)i * 64 * D_DIM + k0,
                        (char*)sB + i * 8192 + ldsW);
        __syncthreads();

        #pragma unroll
        for (int kk = 0; kk < 2; ++kk) {
            const int swzk = kk ? swz1 : swz0;
            short8 a[8], b[4];
            #pragma unroll
            for (int mi = 0; mi < 8; ++mi)
                a[mi] = *(const short8*)(sAb + mi * 16 * 128 + swzk);
            #pragma unroll
            for (int ni = 0; ni < 4; ++ni)
                b[ni] = *(const short8*)(sBb + ni * 16 * 128 + swzk);
            #pragma unroll
            for (int mi = 0; mi < 8; ++mi)
                #pragma unroll
                for (int ni = 0; ni < 4; ++ni)
                    acc[mi][ni] = __builtin_amdgcn_mfma_f32_16x16x32_bf16(
                        a[mi], b[ni], acc[mi][ni], 0, 0, 0);
        }
        __syncthreads();
    }

    // ---- fused epilogue: hyperbolic logits + lane-pair logsumexp ---------
    float* scx = (float*)sA;          // reuse LDS for the cx2 tile
    if (tid < 256) scx[tid] = cx2g[m0 + tid];
    __syncthreads();

    const float gam = gamma_p[0];
    const float ex  = expf(2.0f * gam);
    const float ch2 = ex + 1.0f / ex;           // 2*cosh(2*gamma)
    const float sh  = 0.5f * (ex - 1.0f / ex);  // sinh(2*gamma)

    const int  pan = (n0 >> 6) + wn;            // 64-col panel index
    const int  cls = pan * 8 + (lane & 7);
    const bool wrt = ((lane & 8) == 0) && (cls < C_CLS);
    const float w2 = (cls < C_CLS) ? 2.0f * wgl[cls] : 0.0f;

    #pragma unroll
    for (int mi = 0; mi < 8; ++mi) {
        #pragma unroll
        for (int r = 0; r < 4; ++r) {
            const int mloc = wm * 128 + mi * 16 + ((lane >> 4) << 2) + r;
            const float c2   = scx[mloc];
            const float rden = 1.0f / fmaxf(1.0f - c2, 1e-15f);
            const float tc   = ch2 * rden;
            const float tp   = (1.0f + c2) * sh * rden;
            float bk[4];
            #pragma unroll
            for (int ni = 0; ni < 4; ++ni) {
                const float t = fmaf(acc[mi][ni][r], tc, -tp);
                const float u = fmaxf(t + __fsqrt_rn(fmaf(t, t, 1.0f)), 1e-20f);
                bk[ni] = w2 * __logf(u);
            }
            float mx = fmaxf(fmaxf(bk[0], bk[1]), fmaxf(bk[2], bk[3]));
            mx = fmaxf(mx, __shfl_xor(mx, 8));
            float s = __expf(bk[0] - mx) + __expf(bk[1] - mx)
                    + __expf(bk[2] - mx) + __expf(bk[3] - mx);
            s += __shfl_xor(s, 8);
            if (wrt)
                out[(size_t)(m0 + mloc) * C_CLS + cls] = mx + __logf(s);
        }
    }
}

// --- launch ----------------------------------------------------------------

extern "C" void kernel_launch(void* const* d_in, const int* in_sizes, int n_in,
                              void* d_out, int out_size, void* d_ws, size_t ws_size,
                              hipStream_t stream) {
    const float* x     = (const float*)d_in[0];
    const float* wv    = (const float*)d_in[1];
    const float* wg    = (const float*)d_in[2];
    const float* gamma = (const float*)d_in[3];
    float* out = (float*)d_out;

    char* ws = (char*)d_ws;
    ushort* xb  = (ushort*)ws;                                  // 16,777,216 B
    ushort* zb  = (ushort*)(ws + (size_t)B_ROWS * D_DIM * 2);   // 16,777,216 B
    float*  cx2 = (float*)(ws + (size_t)B_ROWS * D_DIM * 2
                              + (size_t)N_PAD * D_DIM * 2);     //     32,768 B

    prep<<<B_ROWS + N_PAD, 256, 0, stream>>>(x, wv, xb, zb, cx2);
    gemm_epi<<<1024, 512, 0, stream>>>(xb, zb, cx2, wg, gamma, out);
}

// Round 10
// 192.510 us; speedup vs baseline: 1.0724x; 1.0686x over previous
//
#include <hip/hip_runtime.h>
#include <hip/hip_bf16.h>
#include <stdint.h>

// Problem dims
#define B_ROWS 8192
#define D_DIM  1024
#define C_CLS  1000
#define K_PROT 8
#define N_PAD  8192          // 32 * 256 (classes 1000..1023 zero-padded)
#define BKT    64            // K-tile depth (elements)
#define NT     16            // D_DIM / BKT

typedef __attribute__((ext_vector_type(8))) short  short8;   // 8 bf16
typedef __attribute__((ext_vector_type(4))) float  f32x4;    // MFMA acc

// --- helpers -------------------------------------------------------------

__device__ __forceinline__ ushort f2bf(float f) {
    union { float f; uint32_t u; } v; v.f = f;
    uint32_t u = v.u;
    return (ushort)((u + 0x7fffu + ((u >> 16) & 1u)) >> 16);
}

typedef __attribute__((address_space(1))) void gv_t;
typedef __attribute__((address_space(3))) void lv_t;

__device__ __forceinline__ void gload_lds16(const void* g, void* l) {
    // async global->LDS, 16B/lane; LDS dest = wave-uniform base + lane*16
    __builtin_amdgcn_global_load_lds((gv_t*)g, (lv_t*)l, 16, 0, 0);
}

__device__ __forceinline__ float waveReduceSum(float s) {
    #pragma unroll
    for (int m = 32; m >= 1; m >>= 1) s += __shfl_xor(s, m);
    return s;
}

// --- kernel 1: fused prep (layout identical to R9 — verified absmax OK) ---
// blocks 0..8191:      x row b -> bf16 + cx2
// blocks 8192..16383:  weight_v -> normalized bf16, PERMUTED + padded
// zb physical row P encodes (class,k) phase-ordered:
//   pan = (P>>8)*4 + ((P>>5)&3);  ni = 2*((P>>7)&1) + ((P>>4)&1)
//   cls = pan*8 + (P&7);          k  = ni + 4*((P>>3)&1)

__global__ __launch_bounds__(256) void prep(const float* __restrict__ x,
                                            const float* __restrict__ wv,
                                            ushort* __restrict__ xb,
                                            ushort* __restrict__ zb,
                                            float* __restrict__ cx2) {
    const int t = threadIdx.x;
    __shared__ float red[4];

    if ((int)blockIdx.x < B_ROWS) {
        const int b = blockIdx.x;
        const float4 v = ((const float4*)(x + (size_t)b * D_DIM))[t];
        ushort4 o;
        o.x = f2bf(v.x); o.y = f2bf(v.y); o.z = f2bf(v.z); o.w = f2bf(v.w);
        ((ushort4*)(xb + (size_t)b * D_DIM))[t] = o;
        float s = v.x*v.x + v.y*v.y + v.z*v.z + v.w*v.w;
        s = waveReduceSum(s);
        if ((t & 63) == 0) red[t >> 6] = s;
        __syncthreads();
        if (t == 0) cx2[b] = red[0] + red[1] + red[2] + red[3];
        return;
    }

    const int P   = blockIdx.x - B_ROWS;        // 0..N_PAD-1
    const int pan = (P >> 8) * 4 + ((P >> 5) & 3);
    const int ni  = 2 * ((P >> 7) & 1) + ((P >> 4) & 1);
    const int cls = pan * 8 + (P & 7);
    const int k   = ni + 4 * ((P >> 3) & 1);

    if (cls >= C_CLS) {
        ((ushort4*)(zb + (size_t)P * D_DIM))[t] = make_ushort4(0, 0, 0, 0);
        return;
    }
    const int n = cls * K_PROT + k;
    const float4 v = ((const float4*)(wv + (size_t)n * D_DIM))[t];
    float s = v.x*v.x + v.y*v.y + v.z*v.z + v.w*v.w;
    s = waveReduceSum(s);
    if ((t & 63) == 0) red[t >> 6] = s;
    __syncthreads();
    const float n2 = red[0] + red[1] + red[2] + red[3];
    const float rn = 1.0f / fmaxf(sqrtf(n2), 1e-15f);
    ushort4 o;
    o.x = f2bf(v.x * rn); o.y = f2bf(v.y * rn);
    o.z = f2bf(v.z * rn); o.w = f2bf(v.w * rn);
    ((ushort4*)(zb + (size_t)P * D_DIM))[t] = o;
}

// --- kernel 2: 256x256, 8 waves, double-buffered 4-phase pipeline ---------
// CORRECTED SYNC (R9 post-mortem): phase = {ds_reads; stage-issue;
// counted vmcnt; s_barrier; MFMA}. The vmcnt is BEFORE the barrier so the
// barrier PUBLISHES each wave's retirements cross-wave. Ledger:
//   prologue: stage AE,BE,AO,BO(0) [8 loads]; vmcnt(4) retires AE,BE(0); bar
//   q0: read AE,BE(c); stage AE(c+1); vmcnt(4) retires AO(c);      bar; MFMA
//   q1: read AO(c);    stage BE(c+1); vmcnt(4) retires BO(c);      bar; MFMA
//   q2: read AE,BO(c); stage AO(c+1); (no wait)                    bar; MFMA
//   q3: read AO(c);    stage BO(c+1); vmcnt(4) retires AE,BE(c+1); bar; MFMA
// Every cross-wave read is preceded by (issuer vmcnt-retire -> barrier).
// 4-8 loads stay in flight; never drains to 0 until the tail (2/0/-/-).

__global__ __launch_bounds__(512, 2) void gemm_epi(
        const ushort* __restrict__ A,    // [B_ROWS][D_DIM] bf16 (x)
        const ushort* __restrict__ Bz,   // [N_PAD][D_DIM] bf16 (permuted z)
        const float*  __restrict__ cx2g, // [B_ROWS]
        const float*  __restrict__ wgl,  // [C_CLS]
        const float*  __restrict__ gamma_p,
        float*        __restrict__ out)  // [B_ROWS][C_CLS]
{
    __shared__ __attribute__((aligned(128))) char lds[131072];

    const int tid  = threadIdx.x;
    const int lane = tid & 63;
    const int wid  = tid >> 6;        // 0..7
    const int wm   = wid >> 2;        // 0..1 : 128 output rows each
    const int wn   = wid & 3;         // 0..3 : 64 output cols each

    // XCD grid map (R8-proven: FETCH ~99 MB)
    const int bid = blockIdx.x;       // 0..1023
    const int xcd = bid & 7;
    const int j   = bid >> 3;         // 0..127
    const int bn  = xcd * 4 + (j & 3);
    const int bm  = j >> 2;           // 0..31
    const int m0  = bm * 256;
    const int n0  = bn * 256;

    // staging: gload set i covers lds rows i*64..i*64+63; thread t -> row
    // i*64 + (t>>3), 16B slot t&7; source col-group = (t&7)^(row&7) [T2].
    const int stCol = ((tid & 7) ^ ((tid >> 3) & 7)) * 8;
    const int stRow = tid >> 3;                      // 0..63
    const ushort* aSrc0 = A  + (size_t)(m0 + stRow) * D_DIM + stCol;
    const ushort* bSrc0 = Bz + (size_t)(n0 + stRow) * D_DIM + stCol;
    const int ldsW = wid * 1024;      // wave-uniform sub-base within 8KB set

    // fragment reads (128B rows; R6-proven 0-conflict swizzle)
    const int swz0 = ((      (lane >> 4) * 16) ^ ((lane & 7) << 4));
    const int swz1 = ((64 + ((lane >> 4) * 16)) ^ ((lane & 7) << 4));
    const int aBase = (wm * 64 + (lane & 15)) * 128;          // + quad offsets
    const int bBase = 32768 + (wn * 32 + (lane & 15)) * 128;

#define ABYTE(mi) (aBase + ((mi) >> 2) * 16384 + ((mi) & 3) * 2048)
#define BBYTE(ni) (bBase + ((ni) >> 1) * 16384 + ((ni) & 1) * 2048)
#define STG_A(buf, ct, i, roff) \
    gload_lds16(aSrc0 + (size_t)(roff) * D_DIM + (ct) * BKT, (buf) + (i) * 8192 + ldsW)
#define STG_B(buf, ct, i) \
    gload_lds16(bSrc0 + (size_t)(i) * 64 * D_DIM + (ct) * BKT, (buf) + 32768 + (i) * 8192 + ldsW)
#define STAGE_AE(buf, ct) do { STG_A(buf, ct, 0, 0);  STG_A(buf, ct, 1, 128); } while (0)
#define STAGE_AO(buf, ct) do { STG_A(buf, ct, 2, 64); STG_A(buf, ct, 3, 192); } while (0)
#define STAGE_BE(buf, ct) do { STG_B(buf, ct, 0); STG_B(buf, ct, 1); } while (0)
#define STAGE_BO(buf, ct) do { STG_B(buf, ct, 2); STG_B(buf, ct, 3); } while (0)
#define VMC(n) asm volatile("s_waitcnt vmcnt(" #n ")" ::: "memory")
#define BAR()  do { asm volatile("" ::: "memory"); \
    __builtin_amdgcn_s_barrier(); asm volatile("" ::: "memory"); } while (0)

    f32x4 acc[8][4];
    #pragma unroll
    for (int i = 0; i < 8; ++i)
        #pragma unroll
        for (int q = 0; q < 4; ++q) acc[i][q] = (f32x4)(0.0f);

    // prologue: tile 0 fully staged; retire AE,BE(0); PUBLISH via barrier
    {
        char* b0 = lds;
        STAGE_AE(b0, 0); STAGE_BE(b0, 0); STAGE_AO(b0, 0); STAGE_BO(b0, 0);
    }
    VMC(4);
    BAR();

    for (int c = 0; c < NT; ++c) {
        const char* cur = lds + (c & 1) * 65536;
        char*       nxt = lds + ((c + 1) & 1) * 65536;
        const bool  st  = (c + 1 < NT);
        short8 a[4][2], b[2][2];

        // ---- q0: read AE,BE(c); stage AE(c+1); retire AO(c) ----
        #pragma unroll
        for (int mi = 0; mi < 4; ++mi) {
            a[mi][0] = *(const short8*)(cur + ABYTE(mi) + swz0);
            a[mi][1] = *(const short8*)(cur + ABYTE(mi) + swz1);
        }
        #pragma unroll
        for (int ni = 0; ni < 2; ++ni) {
            b[ni][0] = *(const short8*)(cur + BBYTE(ni) + swz0);
            b[ni][1] = *(const short8*)(cur + BBYTE(ni) + swz1);
        }
        if (st) { STAGE_AE(nxt, c + 1); VMC(4); } else { VMC(2); }
        BAR();
        __builtin_amdgcn_s_setprio(1);
        #pragma unroll
        for (int mi = 0; mi < 4; ++mi)
            #pragma unroll
            for (int ni = 0; ni < 2; ++ni) {
                acc[mi][ni] = __builtin_amdgcn_mfma_f32_16x16x32_bf16(
                    a[mi][0], b[ni][0], acc[mi][ni], 0, 0, 0);
                acc[mi][ni] = __builtin_amdgcn_mfma_f32_16x16x32_bf16(
                    a[mi][1], b[ni][1], acc[mi][ni], 0, 0, 0);
            }
        __builtin_amdgcn_s_setprio(0);

        // ---- q1: read AO(c); stage BE(c+1); retire BO(c) ----
        #pragma unroll
        for (int mi = 0; mi < 4; ++mi) {
            a[mi][0] = *(const short8*)(cur + ABYTE(mi + 4) + swz0);
            a[mi][1] = *(const short8*)(cur + ABYTE(mi + 4) + swz1);
        }
        if (st) { STAGE_BE(nxt, c + 1); VMC(4); } else { VMC(0); }
        BAR();
        __builtin_amdgcn_s_setprio(1);
        #pragma unroll
        for (int mi = 0; mi < 4; ++mi)
            #pragma unroll
            for (int ni = 0; ni < 2; ++ni) {
                acc[mi + 4][ni] = __builtin_amdgcn_mfma_f32_16x16x32_bf16(
                    a[mi][0], b[ni][0], acc[mi + 4][ni], 0, 0, 0);
                acc[mi + 4][ni] = __builtin_amdgcn_mfma_f32_16x16x32_bf16(
                    a[mi][1], b[ni][1], acc[mi + 4][ni], 0, 0, 0);
            }
        __builtin_amdgcn_s_setprio(0);

        // ---- q2: read AE(c),BO(c); stage AO(c+1); no wait ----
        #pragma unroll
        for (int mi = 0; mi < 4; ++mi) {
            a[mi][0] = *(const short8*)(cur + ABYTE(mi) + swz0);
            a[mi][1] = *(const short8*)(cur + ABYTE(mi) + swz1);
        }
        #pragma unroll
        for (int ni = 0; ni < 2; ++ni) {
            b[ni][0] = *(const short8*)(cur + BBYTE(ni + 2) + swz0);
            b[ni][1] = *(const short8*)(cur + BBYTE(ni + 2) + swz1);
        }
        if (st) STAGE_AO(nxt, c + 1);
        BAR();
        __builtin_amdgcn_s_setprio(1);
        #pragma unroll
        for (int mi = 0; mi < 4; ++mi)
            #pragma unroll
            for (int ni = 0; ni < 2; ++ni) {
                acc[mi][ni + 2] = __builtin_amdgcn_mfma_f32_16x16x32_bf16(
                    a[mi][0], b[ni][0], acc[mi][ni + 2], 0, 0, 0);
                acc[mi][ni + 2] = __builtin_amdgcn_mfma_f32_16x16x32_bf16(
                    a[mi][1], b[ni][1], acc[mi][ni + 2], 0, 0, 0);
            }
        __builtin_amdgcn_s_setprio(0);

        // ---- q3: read AO(c); stage BO(c+1); retire AE,BE(c+1) ----
        #pragma unroll
        for (int mi = 0; mi < 4; ++mi) {
            a[mi][0] = *(const short8*)(cur + ABYTE(mi + 4) + swz0);
            a[mi][1] = *(const short8*)(cur + ABYTE(mi + 4) + swz1);
        }
        if (st) { STAGE_BO(nxt, c + 1); VMC(4); }
        BAR();
        __builtin_amdgcn_s_setprio(1);
        #pragma unroll
        for (int mi = 0; mi < 4; ++mi)
            #pragma unroll
            for (int ni = 0; ni < 2; ++ni) {
                acc[mi + 4][ni + 2] = __builtin_amdgcn_mfma_f32_16x16x32_bf16(
                    a[mi][0], b[ni][0], acc[mi + 4][ni + 2], 0, 0, 0);
                acc[mi + 4][ni + 2] = __builtin_amdgcn_mfma_f32_16x16x32_bf16(
                    a[mi][1], b[ni][1], acc[mi + 4][ni + 2], 0, 0, 0);
            }
        __builtin_amdgcn_s_setprio(0);
    }

    // ---- fused epilogue: hyperbolic logits + lane-pair logsumexp ---------
    __syncthreads();                   // drains all counters before LDS reuse
    float* scx = (float*)lds;
    if (tid < 256) scx[tid] = cx2g[m0 + tid];
    __syncthreads();

    const float gam = gamma_p[0];
    const float ex  = expf(2.0f * gam);
    const float ch2 = ex + 1.0f / ex;           // 2*cosh(2*gamma)
    const float sh  = 0.5f * (ex - 1.0f / ex);  // sinh(2*gamma)

    const int  pan = bn * 4 + wn;               // 64-col panel index
    const int  cls = pan * 8 + (lane & 7);
    const bool wrt = ((lane & 8) == 0) && (cls < C_CLS);
    const float w2 = (cls < C_CLS) ? 2.0f * wgl[cls] : 0.0f;

    #pragma unroll
    for (int mi = 0; mi < 8; ++mi) {
        #pragma unroll
        for (int r = 0; r < 4; ++r) {
            const int mloc = wm * 128 + mi * 16 + ((lane >> 4) << 2) + r;
            const float c2   = scx[mloc];
            const float rden = 1.0f / fmaxf(1.0f - c2, 1e-15f);
            const float tc   = ch2 * rden;
            const float tp   = (1.0f + c2) * sh * rden;
            float bk[4];
            #pragma unroll
            for (int ni = 0; ni < 4; ++ni) {
                const float t = fmaf(acc[mi][ni][r], tc, -tp);
                const float u = fmaxf(t + __fsqrt_rn(fmaf(t, t, 1.0f)), 1e-20f);
                bk[ni] = w2 * __logf(u);
            }
            float mx = fmaxf(fmaxf(bk[0], bk[1]), fmaxf(bk[2], bk[3]));
            mx = fmaxf(mx, __shfl_xor(mx, 8));
            float s = __expf(bk[0] - mx) + __expf(bk[1] - mx)
                    + __expf(bk[2] - mx) + __expf(bk[3] - mx);
            s += __shfl_xor(s, 8);
            if (wrt)
                out[(size_t)(m0 + mloc) * C_CLS + cls] = mx + __logf(s);
        }
    }
#undef ABYTE
#undef BBYTE
#undef STG_A
#undef STG_B
#undef STAGE_AE
#undef STAGE_AO
#undef STAGE_BE
#undef STAGE_BO
#undef VMC
#undef BAR
}

// --- launch ----------------------------------------------------------------

extern "C" void kernel_launch(void* const* d_in, const int* in_sizes, int n_in,
                              void* d_out, int out_size, void* d_ws, size_t ws_size,
                              hipStream_t stream) {
    const float* x     = (const float*)d_in[0];
    const float* wv    = (const float*)d_in[1];
    const float* wg    = (const float*)d_in[2];
    const float* gamma = (const float*)d_in[3];
    float* out = (float*)d_out;

    char* ws = (char*)d_ws;
    ushort* xb  = (ushort*)ws;                                  // 16,777,216 B
    ushort* zb  = (ushort*)(ws + (size_t)B_ROWS * D_DIM * 2);   // 16,777,216 B
    float*  cx2 = (float*)(ws + (size_t)B_ROWS * D_DIM * 2
                              + (size_t)N_PAD * D_DIM * 2);     //     32,768 B

    prep<<<B_ROWS + N_PAD, 256, 0, stream>>>(x, wv, xb, zb, cx2);
    gemm_epi<<<1024, 512, 0, stream>>>(xb, zb, cx2, wg, gamma, out);
}

// Round 11
// 168.151 us; speedup vs baseline: 1.2278x; 1.1449x over previous
//
#include <hip/hip_runtime.h>
#include <hip/hip_bf16.h>
#include <stdint.h>

// Problem dims
#define B_ROWS 8192
#define D_DIM  1024
#define C_CLS  1000
#define K_PROT 8
#define N_PAD  8064          // 63 * 128 zero-padded prototype columns
#define BM2    256
#define BN2    128
#define BKT    64            // K-tile depth (elements)
#define NTI    16            // D_DIM / BKT

typedef __attribute__((ext_vector_type(8))) short  short8;   // 8 bf16
typedef __attribute__((ext_vector_type(4))) float  f32x4;    // MFMA acc

// --- helpers -------------------------------------------------------------

__device__ __forceinline__ ushort f2bf(float f) {
    union { float f; uint32_t u; } v; v.f = f;
    uint32_t u = v.u;
    return (ushort)((u + 0x7fffu + ((u >> 16) & 1u)) >> 16);
}

typedef __attribute__((address_space(1))) void gv_t;
typedef __attribute__((address_space(3))) void lv_t;

__device__ __forceinline__ void gload_lds16(const void* g, void* l) {
    // async global->LDS, 16B/lane; LDS dest = wave-uniform base + lane*16
    __builtin_amdgcn_global_load_lds((gv_t*)g, (lv_t*)l, 16, 0, 0);
}

__device__ __forceinline__ float waveReduceSum(float s) {
    #pragma unroll
    for (int m = 32; m >= 1; m >>= 1) s += __shfl_xor(s, m);
    return s;
}

// --- kernel 1: fused prep -------------------------------------------------
// blocks 0..8191:       x row b -> bf16 + cx2 = sum(x^2)
// blocks 8192..16255:   weight_v -> normalized bf16, PERMUTED + padded
// Column permutation (R6-verified): physical col P: gpan=P>>6 (64-col
// panel), ni=(P>>4)&3, cc=P&15; class = gpan*8 + (cc&7), k = ni+4*(cc>>3)
// -> all 8 k's of a class land in lane pair (lane, lane^8) of the epilogue.

__global__ __launch_bounds__(256) void prep(const float* __restrict__ x,
                                            const float* __restrict__ wv,
                                            ushort* __restrict__ xb,
                                            ushort* __restrict__ zb,
                                            float* __restrict__ cx2) {
    const int t = threadIdx.x;
    __shared__ float red[4];

    if ((int)blockIdx.x < B_ROWS) {
        const int b = blockIdx.x;
        const float4 v = ((const float4*)(x + (size_t)b * D_DIM))[t];
        ushort4 o;
        o.x = f2bf(v.x); o.y = f2bf(v.y); o.z = f2bf(v.z); o.w = f2bf(v.w);
        ((ushort4*)(xb + (size_t)b * D_DIM))[t] = o;
        float s = v.x*v.x + v.y*v.y + v.z*v.z + v.w*v.w;
        s = waveReduceSum(s);
        if ((t & 63) == 0) red[t >> 6] = s;
        __syncthreads();
        if (t == 0) cx2[b] = red[0] + red[1] + red[2] + red[3];
        return;
    }

    const int P    = blockIdx.x - B_ROWS;       // 0..N_PAD-1
    const int gpan = P >> 6;
    const int ni   = (P >> 4) & 3;
    const int cc   = P & 15;
    const int cls  = gpan * 8 + (cc & 7);
    const int k    = ni + ((cc >> 3) << 2);

    if (cls >= C_CLS) {
        ((ushort4*)(zb + (size_t)P * D_DIM))[t] = make_ushort4(0, 0, 0, 0);
        return;
    }
    const int n = cls * K_PROT + k;
    const float4 v = ((const float4*)(wv + (size_t)n * D_DIM))[t];
    float s = v.x*v.x + v.y*v.y + v.z*v.z + v.w*v.w;
    s = waveReduceSum(s);
    if ((t & 63) == 0) red[t >> 6] = s;
    __syncthreads();
    const float n2 = red[0] + red[1] + red[2] + red[3];
    const float rn = 1.0f / fmaxf(sqrtf(n2), 1e-15f);
    ushort4 o;
    o.x = f2bf(v.x * rn); o.y = f2bf(v.y * rn);
    o.z = f2bf(v.z * rn); o.w = f2bf(v.w * rn);
    ((ushort4*)(zb + (size_t)P * D_DIM))[t] = o;
}

// --- kernel 2: 256x128 block, 4 waves (128x64 each) — R6 GEMM verbatim ----
// Best measured structure (R6: 170.7 us bench, ~878 TF effective GEMM,
// MfmaUtil 27, 0 bank conflicts). 48 KB LDS -> ~2.5 blocks/CU co-resident;
// cross-block TLP fills barrier stalls (m114 mechanism). The five 1-block/CU
// pipelined variants (R4/R5/R7/R9/R10) all regressed to MfmaUtil 21-23.

__global__ __launch_bounds__(256, 2) void gemm_epi(
        const ushort* __restrict__ A,    // [B_ROWS][D_DIM] bf16 (x)
        const ushort* __restrict__ Bz,   // [N_PAD][D_DIM] bf16 (permuted z)
        const float*  __restrict__ cx2g, // [B_ROWS]
        const float*  __restrict__ wgl,  // [C_CLS]
        const float*  __restrict__ gamma_p,
        float*        __restrict__ out)  // [B_ROWS][C_CLS]
{
    __shared__ __attribute__((aligned(16))) ushort sA[BM2 * BKT]; // 32 KB
    __shared__ __attribute__((aligned(16))) ushort sB[BN2 * BKT]; // 16 KB

    const int tid  = threadIdx.x;
    const int lane = tid & 63;
    const int w    = tid >> 6;        // wave 0..3
    const int wm   = w >> 1;          // 0..1 : 128 output rows each
    const int wn   = w & 1;           // 0..1 : 64 output cols each

    // bm fastest: 32 consecutive blocks share one B-panel (256 KB L2-hot)
    const int bm = blockIdx.x & 31;
    const int bn = blockIdx.x >> 5;   // 0..62
    const int m0 = bm * BM2;
    const int n0 = bn * BN2;

    // staging: thread covers row (tid>>3) within each 32-row group; source
    // col-group = (lane&7) ^ (row&7)  [T2 swizzle, source side; row&7 = lane>>3]
    const int stCol = ((lane & 7) ^ (lane >> 3)) * 8;
    const ushort* aS = A  + (size_t)(m0 + (tid >> 3)) * D_DIM + stCol;
    const ushort* bS = Bz + (size_t)(n0 + (tid >> 3)) * D_DIM + stCol;

    // fragment read addressing (rows are 128 B; swizzled 16B slot)
    const int swz0 = ((      (lane >> 4) * 16) ^ ((lane & 7) << 4));
    const int swz1 = ((64 + ((lane >> 4) * 16)) ^ ((lane & 7) << 4));
    const char* sAb = (const char*)sA + (wm * 128 + (lane & 15)) * 128;
    const char* sBb = (const char*)sB + (wn * 64  + (lane & 15)) * 128;

    f32x4 acc[8][4];
    #pragma unroll
    for (int mi = 0; mi < 8; ++mi)
        #pragma unroll
        for (int ni = 0; ni < 4; ++ni)
            acc[mi][ni] = (f32x4)(0.0f);

    for (int t = 0; t < NTI; ++t) {
        const int k0 = t * BKT;
        // stage A (8 x 32-row groups) and B (4 x 32-row groups)
        #pragma unroll
        for (int i = 0; i < 8; ++i)
            gload_lds16(aS + (size_t)i * 32 * D_DIM + k0,
                        (char*)sA + i * 4096 + w * 1024);
        #pragma unroll
        for (int i = 0; i < 4; ++i)
            gload_lds16(bS + (size_t)i * 32 * D_DIM + k0,
                        (char*)sB + i * 4096 + w * 1024);
        __syncthreads();

        #pragma unroll
        for (int kk = 0; kk < 2; ++kk) {
            const int swzk = kk ? swz1 : swz0;
            short8 a[8], b[4];
            #pragma unroll
            for (int mi = 0; mi < 8; ++mi)
                a[mi] = *(const short8*)(sAb + mi * 16 * 128 + swzk);
            #pragma unroll
            for (int ni = 0; ni < 4; ++ni)
                b[ni] = *(const short8*)(sBb + ni * 16 * 128 + swzk);
            #pragma unroll
            for (int mi = 0; mi < 8; ++mi)
                #pragma unroll
                for (int ni = 0; ni < 4; ++ni)
                    acc[mi][ni] = __builtin_amdgcn_mfma_f32_16x16x32_bf16(
                        a[mi], b[ni], acc[mi][ni], 0, 0, 0);
        }
        __syncthreads();
    }

    // ---- fused epilogue: hyperbolic logits + lane-pair logsumexp ---------
    float* scx = (float*)sA;          // reuse LDS for the cx2 tile
    scx[tid] = cx2g[m0 + tid];        // 256 threads = 256 rows
    __syncthreads();

    const float gam = gamma_p[0];
    const float ex  = expf(2.0f * gam);
    const float ch2 = ex + 1.0f / ex;           // 2*cosh(2*gamma)
    const float sh  = 0.5f * (ex - 1.0f / ex);  // sinh(2*gamma)

    const int  pan = (n0 >> 6) + wn;            // 64-col panel index
    const int  cls = pan * 8 + (lane & 7);
    const bool wrt = ((lane & 8) == 0) && (cls < C_CLS);
    const float w2 = (cls < C_CLS) ? 2.0f * wgl[cls] : 0.0f;

    #pragma unroll
    for (int mi = 0; mi < 8; ++mi) {
        #pragma unroll
        for (int r = 0; r < 4; ++r) {
            const int mloc = wm * 128 + mi * 16 + ((lane >> 4) << 2) + r;
            const float c2   = scx[mloc];
            const float rden = 1.0f / fmaxf(1.0f - c2, 1e-15f);
            const float tc   = ch2 * rden;
            const float tp   = (1.0f + c2) * sh * rden;
            float bk[4];
            #pragma unroll
            for (int ni = 0; ni < 4; ++ni) {
                const float t = fmaf(acc[mi][ni][r], tc, -tp);
                const float u = fmaxf(t + __fsqrt_rn(fmaf(t, t, 1.0f)), 1e-20f);
                bk[ni] = w2 * __logf(u);
            }
            float mx = fmaxf(fmaxf(bk[0], bk[1]), fmaxf(bk[2], bk[3]));
            mx = fmaxf(mx, __shfl_xor(mx, 8));
            float s = __expf(bk[0] - mx) + __expf(bk[1] - mx)
                    + __expf(bk[2] - mx) + __expf(bk[3] - mx);
            s += __shfl_xor(s, 8);
            if (wrt)
                out[(size_t)(m0 + mloc) * C_CLS + cls] = mx + __logf(s);
        }
    }
}

// --- launch ----------------------------------------------------------------

extern "C" void kernel_launch(void* const* d_in, const int* in_sizes, int n_in,
                              void* d_out, int out_size, void* d_ws, size_t ws_size,
                              hipStream_t stream) {
    const float* x     = (const float*)d_in[0];
    const float* wv    = (const float*)d_in[1];
    const float* wg    = (const float*)d_in[2];
    const float* gamma = (const float*)d_in[3];
    float* out = (float*)d_out;

    char* ws = (char*)d_ws;
    ushort* xb  = (ushort*)ws;                                  // 16,777,216 B
    ushort* zb  = (ushort*)(ws + (size_t)B_ROWS * D_DIM * 2);   // 16,515,072 B
    float*  cx2 = (float*)(ws + (size_t)B_ROWS * D_DIM * 2
                              + (size_t)N_PAD * D_DIM * 2);     //     32,768 B

    prep<<<B_ROWS + N_PAD, 256, 0, stream>>>(x, wv, xb, zb, cx2);
    gemm_epi<<<32 * 63, 256, 0, stream>>>(xb, zb, cx2, wg, gamma, out);
}